// Round 11
// baseline (1657.313 us; speedup 1.0000x reference)
//
#include <hip/hip_runtime.h>
#include <hip/hip_bf16.h>

#define BATCH 256
#define SEQ   250
#define HID   512
#define INDIM 5

#define NBLK  256
#define MB    32   // batch rows per block (8 batch tiles = 8 barrier groups)
#define HB    16   // hidden units per block (32 hidden tiles = 32 group members)

// member-major h buffers: slot s (2) | group bt (8) | member j (32) | 1KB
//   member block global: j*1024 + row*32 + col*2   (32 rows x 16 cols bf16)
// LDS copy: 48B row stride (conflict-free b128 fragment reads)
#define LROW 24          // ushorts per LDS row (48B)
#define LMEM 768         // ushorts per member block (32*24)
#define SLOT_BYTES (BATCH * HID * 2)   // 256KB per slot

typedef __attribute__((ext_vector_type(8))) short short8;
typedef __attribute__((ext_vector_type(4))) float f32x4;
typedef __attribute__((ext_vector_type(4))) unsigned int u32x4;

__device__ __forceinline__ float sigmoidf_fast(float x) {
  return 1.0f / (1.0f + __expf(-x));
}
__device__ __forceinline__ float tanhf_fast(float x) {
  return 2.0f / (1.0f + __expf(-2.0f * x)) - 1.0f;
}
__device__ __forceinline__ unsigned short f2bf_rne(float x) {
  union { float f; unsigned u; } v; v.f = x;
  unsigned r = v.u + 0x7fffu + ((v.u >> 16) & 1u);
  return (unsigned short)(r >> 16);
}
__device__ __forceinline__ float bf2f(unsigned short h) {
  union { unsigned u; float f; } v; v.u = ((unsigned)h) << 16;
  return v.f;
}

// R11 = R10 + (a) x-projection hoisted to step start (overlaps the flag
// wait; post-sync#2 act phase is now 8 LDS reads + transcendentals only),
// (b) W_ih/bias held in registers (removes 40 LDS reads + 40 FMAs from the
// serial tail), (c) MALL-escape interval 16 -> 48 L2 probes (cuts the
// straggler tax when a poller sits in a ~700cyc MALL probe as its flag
// turns). Protocol (per-(member,wave) flags, 2 syncs/step, dual-publish
// L2+MALL escape) unchanged from R10 -- proven deadlock-free.
__global__ __launch_bounds__(256, 2) void lstm_persist(
    const float* __restrict__ strokes, const float* __restrict__ W_ih,
    const float* __restrict__ W_hh, const float* __restrict__ b_ih,
    const float* __restrict__ b_hh, const float* __restrict__ W_out,
    const float* __restrict__ b_out, float* __restrict__ out,
    unsigned short* __restrict__ hbuf,   // 2 slots * 256KB, member-major
    int* __restrict__ flagsML,           // 8*32*16 ints, MALL copy (poison<0)
    int* __restrict__ flagsL2,           // 8*32*16 ints, L2 copy   (poison<0)
    int* __restrict__ xcd_ids,           // 256 ints (poison < 0)
    int* __restrict__ vflag)             // 8*16 ints verdicts (poison < 0)
{
  const int tid  = threadIdx.x;
  const int bid  = blockIdx.x;
  const int bt   = bid & 7;      // batch tile / barrier group
  const int ht   = bid >> 3;     // hidden tile 0..31 / group member
  const int wv   = tid >> 6;     // wave id = gate type 0..3 (i,f,g,o)
  const int lane = tid & 63;
  const int n16  = lane & 15;
  const int q    = lane >> 4;

  __shared__ unsigned short h_lds[32 * LMEM];     // 48KB member-major h tile
  __shared__ float g_lds[4][MB][17];              // gate values, padded
  __shared__ int fast_s;

  // ---- publish my XCC id (device scope)
  unsigned xcc;
  asm volatile("s_getreg_b32 %0, hwreg(HW_REG_XCC_ID)" : "=s"(xcc));
  xcc &= 0xfu;
  if (tid == 0) {
    __hip_atomic_store(&xcd_ids[bid], (int)xcc, __ATOMIC_RELAXED,
                       __HIP_MEMORY_SCOPE_AGENT);
  }
  // ---- leader (bid<8) computes group-uniform verdict, BOUNDED poll
  if (bid < 8 && wv == 0) {
    int other = (int)xcc;
    if (lane < 32) {
      const int* xp = &xcd_ids[bid + 8 * lane];
      other = -1;
      for (int it = 0; it < 16384 && other < 0; ++it) {
        other = __hip_atomic_load(xp, __ATOMIC_RELAXED, __HIP_MEMORY_SCOPE_AGENT);
      }
    }
    unsigned long long ok = __ballot(other == (int)xcc);
    if (lane == 0) {
      __hip_atomic_store(&vflag[bid * 16], (ok == ~0ull) ? 2 : 1,
                         __ATOMIC_RELAXED, __HIP_MEMORY_SCOPE_AGENT);
    }
  }
  if (tid == 0) {   // wait leader (co-resident, bounded work -> terminates)
    int v;
    do {
      v = __hip_atomic_load(&vflag[bt * 16], __ATOMIC_RELAXED,
                            __HIP_MEMORY_SCOPE_AGENT);
    } while (v <= 0);
    fast_s = (v == 2) ? 1 : 0;
  }

  // activation-phase mapping: thread -> (batch row am, hidden pair aj)
  const int am = tid >> 3;            // 0..31
  const int aj = (tid & 7) * 2;       // 0,2,..,14
  const int ab = bt * MB + am;        // global batch row
  const int j0 = wv * 8;              // this wave's first member

  // ---- W_ih slice + combined biases in REGISTERS (per-thread, 48 VGPRs)
  float wih_reg[4][2][INDIM];
  float xbias[4][2];
  #pragma unroll
  for (int g = 0; g < 4; ++g) {
    #pragma unroll
    for (int e = 0; e < 2; ++e) {
      const int r = g * HID + ht * HB + aj + e;
      #pragma unroll
      for (int i = 0; i < INDIM; ++i) wih_reg[g][e][i] = W_ih[r * INDIM + i];
      xbias[g][e] = b_ih[r] + b_hh[r];
    }
  }

  // ---- preload W_hh as bf16 MFMA B-fragments, rotated: wfrag[i] <-> kb=(wv*4+i)&15
  short8 wfrag[16];
  {
    const float* wr = W_hh + (size_t)(wv * HID + ht * HB + n16) * HID;
    #pragma unroll
    for (int i = 0; i < 16; ++i) {
      const int kb = (wv * 4 + i) & 15;
      const float* p = wr + kb * 32 + q * 8;
      short8 f;
      #pragma unroll
      for (int j = 0; j < 8; ++j) f[j] = (short)f2bf_rne(p[j]);
      wfrag[i] = f;
    }
  }
  __syncthreads();
  const bool fast = fast_s != 0;

  float c0 = 0.f, c1 = 0.f;

  for (int t = 0; t < SEQ; ++t) {
    unsigned short* hprev = hbuf + (((t & 1) ^ 1) ? (SLOT_BYTES / 2) : 0);
    unsigned short* hcur  = hbuf + ((t & 1) ? (SLOT_BYTES / 2) : 0);

    // ---- x-projection for this step, computed BEFORE the poll (overlaps
    // the wait window; independent of h)
    float xp[4][2];
    {
      const float* sp = strokes + ((size_t)ab * SEQ + t) * INDIM;
      const float s0 = sp[0], s1 = sp[1], s2 = sp[2], s3 = sp[3], s4 = sp[4];
      #pragma unroll
      for (int g = 0; g < 4; ++g) {
        #pragma unroll
        for (int e = 0; e < 2; ++e) {
          xp[g][e] = xbias[g][e]
                   + s0 * wih_reg[g][e][0] + s1 * wih_reg[g][e][1]
                   + s2 * wih_reg[g][e][2] + s3 * wih_reg[g][e][3]
                   + s4 * wih_reg[g][e][4];
        }
      }
    }

    f32x4 acc[2][2] = {};
    if (t > 0) {
      // ---- poll 8 members x 4 wave-flags (lanes 0..31), with MALL escape
      if (lane < 32) {
        const int fi = (bt * 32 + (j0 + (lane >> 2))) * 16 + (lane & 3) * 4;
        const int* fpL = &flagsL2[fi];
        const int* fpM = &flagsML[fi];
        if (fast) {
          int v = -1;
          while (v < t) {
            #pragma unroll 1
            for (int p = 0; p < 48 && v < t; ++p) {
              asm volatile("global_load_dword %0, %1, off sc0\n\t"
                           "s_waitcnt vmcnt(0)"
                           : "=v"(v) : "v"(fpL) : "memory");
            }
            if (v < t) {
              v = __hip_atomic_load(fpM, __ATOMIC_RELAXED,
                                    __HIP_MEMORY_SCOPE_AGENT);
            }
          }
        } else {
          while (__hip_atomic_load(fpM, __ATOMIC_RELAXED,
                                   __HIP_MEMORY_SCOPE_AGENT) < t) { }
        }
      }
      // ---- stage this wave's 8 members (8 x 1KB) into LDS
      const char* base = reinterpret_cast<const char*>(hprev) + bt * 32768;
      u32x4 tmp[8];
      if (fast) {
        #pragma unroll
        for (int m = 0; m < 8; ++m)
          asm volatile("global_load_dwordx4 %0, %1, off sc0"
                       : "=v"(tmp[m])
                       : "v"(base + (j0 + m) * 1024 + lane * 16) : "memory");
      } else {
        #pragma unroll
        for (int m = 0; m < 8; ++m)
          asm volatile("global_load_dwordx4 %0, %1, off sc0 sc1"
                       : "=v"(tmp[m])
                       : "v"(base + (j0 + m) * 1024 + lane * 16) : "memory");
      }
      asm volatile("s_waitcnt vmcnt(0)" ::: "memory");
      #pragma unroll
      for (int m = 0; m < 8; ++m) {
        // bytes lane*16 of member block -> row = lane>>1, half = lane&1
        *reinterpret_cast<u32x4*>(
            &h_lds[(j0 + m) * LMEM + (lane >> 1) * LROW + (lane & 1) * 8]) = tmp[m];
      }

      // ---- early MFMA: the 4 kb this wave itself staged (i = 0..3)
      #pragma unroll
      for (int i = 0; i < 4; ++i) {
        const int kb   = wv * 4 + i;               // own range, <16
        const int jm   = kb * 2 + (q >> 1);
        const int koff = jm * LMEM + (q & 1) * 8;
        #pragma unroll
        for (int mt = 0; mt < 2; ++mt) {
          const int row = mt * 16 + n16;
          const short8 a = *reinterpret_cast<const short8*>(
              &h_lds[koff + row * LROW]);
          acc[mt][i & 1] = __builtin_amdgcn_mfma_f32_16x16x32_bf16(
              a, wfrag[i], acc[mt][i & 1], 0, 0, 0);
        }
      }
      __syncthreads();   // sync#1: all waves' staging visible
      #pragma unroll
      for (int i = 4; i < 16; ++i) {
        const int kb   = (wv * 4 + i) & 15;
        const int jm   = kb * 2 + (q >> 1);
        const int koff = jm * LMEM + (q & 1) * 8;
        #pragma unroll
        for (int mt = 0; mt < 2; ++mt) {
          const int row = mt * 16 + n16;
          const short8 a = *reinterpret_cast<const short8*>(
              &h_lds[koff + row * LROW]);
          acc[mt][i & 1] = __builtin_amdgcn_mfma_f32_16x16x32_bf16(
              a, wfrag[i], acc[mt][i & 1], 0, 0, 0);
        }
      }
    }

    // C-layout: col = lane&15, row = q*4 + reg
    #pragma unroll
    for (int mt = 0; mt < 2; ++mt) {
      #pragma unroll
      for (int r = 0; r < 4; ++r) {
        g_lds[wv][mt * 16 + q * 4 + r][n16] = acc[mt][0][r] + acc[mt][1][r];
      }
    }
    __syncthreads();   // sync#2: gates visible to all waves

    float hv[2];
    #pragma unroll
    for (int e = 0; e < 2; ++e) {
      const int j = aj + e;
      float pre[4];
      #pragma unroll
      for (int g = 0; g < 4; ++g) {
        pre[g] = xp[g][e] + g_lds[g][am][j];
      }
      float ig = sigmoidf_fast(pre[0]);
      float fg = sigmoidf_fast(pre[1]);
      float gg = tanhf_fast(pre[2]);
      float og = sigmoidf_fast(pre[3]);
      float& c = e ? c1 : c0;
      c = fg * c + ig * gg;
      hv[e] = og * tanhf_fast(c);
    }
    // h store, member-major: member ht's 1KB at bt*32KB + ht*1KB
    unsigned pack = (unsigned)f2bf_rne(hv[0]) | ((unsigned)f2bf_rne(hv[1]) << 16);
    unsigned* hp = reinterpret_cast<unsigned*>(
        reinterpret_cast<char*>(hcur) + bt * 32768 + ht * 1024 + am * 32 + aj * 2);
    if (fast) {
      asm volatile("global_store_dword %0, %1, off sc0"
                   :: "v"(hp), "v"(pack) : "memory");
    } else {
      __hip_atomic_store(hp, pack, __ATOMIC_RELAXED, __HIP_MEMORY_SCOPE_AGENT);
    }

    // ---- per-wave publish: drain OWN wave's h stores, then flag (no sync#3)
    asm volatile("s_waitcnt vmcnt(0)" ::: "memory");
    const int gen = t + 1;
    if (lane == 0) {
      const int fi = (bt * 32 + ht) * 16 + wv * 4;
      if (fast) {
        asm volatile("global_store_dword %0, %1, off sc0"
                     :: "v"(&flagsL2[fi]), "v"(gen) : "memory");
      }
      __hip_atomic_store(&flagsML[fi], gen, __ATOMIC_RELAXED,
                         __HIP_MEMORY_SCOPE_AGENT);   // MALL escape copy
    }
    // next iteration's poll (or the final-proj poll) is the consumer wait
  }

  // ---- final projection: member ht==0 of each group, 32 rows.
  if (ht == 0) {
    if (lane < 32) {
      const int fi = (bt * 32 + (j0 + (lane >> 2))) * 16 + (lane & 3) * 4;
      const int* fpL = &flagsL2[fi];
      const int* fpM = &flagsML[fi];
      if (fast) {
        int v = -1;
        while (v < SEQ) {
          #pragma unroll 1
          for (int p = 0; p < 48 && v < SEQ; ++p) {
            asm volatile("global_load_dword %0, %1, off sc0\n\t"
                         "s_waitcnt vmcnt(0)"
                         : "=v"(v) : "v"(fpL) : "memory");
          }
          if (v < SEQ) {
            v = __hip_atomic_load(fpM, __ATOMIC_RELAXED,
                                  __HIP_MEMORY_SCOPE_AGENT);
          }
        }
      } else {
        while (__hip_atomic_load(fpM, __ATOMIC_RELAXED,
                                 __HIP_MEMORY_SCOPE_AGENT) < SEQ) { }
      }
    }
    const char* base = reinterpret_cast<const char*>(hbuf)
                     + ((SEQ - 1) & 1) * SLOT_BYTES + bt * 32768;
    u32x4 tmp[8];
    if (fast) {
      #pragma unroll
      for (int m = 0; m < 8; ++m)
        asm volatile("global_load_dwordx4 %0, %1, off sc0"
                     : "=v"(tmp[m])
                     : "v"(base + (j0 + m) * 1024 + lane * 16) : "memory");
    } else {
      #pragma unroll
      for (int m = 0; m < 8; ++m)
        asm volatile("global_load_dwordx4 %0, %1, off sc0 sc1"
                     : "=v"(tmp[m])
                     : "v"(base + (j0 + m) * 1024 + lane * 16) : "memory");
    }
    asm volatile("s_waitcnt vmcnt(0)" ::: "memory");
    #pragma unroll
    for (int m = 0; m < 8; ++m) {
      *reinterpret_cast<u32x4*>(
          &h_lds[(j0 + m) * LMEM + (lane >> 1) * LROW + (lane & 1) * 8]) = tmp[m];
    }
    __syncthreads();
    if (tid < 32) {
      const int b = bt * MB + tid;
      float s = 0.f;
      for (int k = 0; k < HID; ++k) {
        s += bf2f(h_lds[(k >> 4) * LMEM + tid * LROW + (k & 15)]) * W_out[k];
      }
      float raw = s + b_out[0];
      float lr = raw > 0.f ? raw : 0.1f * raw;
      out[b] = 1.0f / (1.0f + __expf(-lr));
    }
  }
}

extern "C" void kernel_launch(void* const* d_in, const int* in_sizes, int n_in,
                              void* d_out, int out_size, void* d_ws, size_t ws_size,
                              hipStream_t stream) {
  const float* strokes = (const float*)d_in[0];
  const float* W_ih    = (const float*)d_in[1];
  const float* W_hh    = (const float*)d_in[2];
  const float* b_ih    = (const float*)d_in[3];
  const float* b_hh    = (const float*)d_in[4];
  const float* W_out   = (const float*)d_in[5];
  const float* b_out   = (const float*)d_in[6];
  float* out = (float*)d_out;

  char* ws = (char*)d_ws;
  unsigned short* hbuf = (unsigned short*)ws;                 // 512 KB (2 slots)
  size_t off = (size_t)2 * SLOT_BYTES;
  int* flagsML = (int*)(ws + off);  off += 16384;             // 16 KB
  int* flagsL2 = (int*)(ws + off);  off += 16384;             // 16 KB
  int* xcd_ids = (int*)(ws + off);  off += 1024;              // 1 KB
  int* vflag   = (int*)(ws + off);                            // 512 B

  lstm_persist<<<NBLK, 256, 0, stream>>>(strokes, W_ih, W_hh, b_ih, b_hh,
                                         W_out, b_out, out, hbuf,
                                         flagsML, flagsL2, xcd_ids, vflag);
}

// Round 12
// 1046.324 us; speedup vs baseline: 1.5839x; 1.5839x over previous
//
#include <hip/hip_runtime.h>
#include <hip/hip_bf16.h>

#define BATCH 256
#define SEQ   250
#define HID   512
#define INDIM 5

#define NBLK  256
#define MB    32   // batch rows per block (8 batch tiles = 8 barrier groups)
#define HB    16   // hidden units per block (32 hidden tiles = 32 group members)

// member-major h buffers: slot s (2) | group bt (8) | member j (32) | 1KB
//   member block global: j*1024 + row*32 + col*2   (32 rows x 16 cols bf16)
// LDS copy: 48B row stride (conflict-free b128 fragment reads)
#define LROW 24          // ushorts per LDS row (48B)
#define LMEM 768         // ushorts per member block (32*24)
#define SLOT_BYTES (BATCH * HID * 2)   // 256KB per slot

typedef __attribute__((ext_vector_type(8))) short short8;
typedef __attribute__((ext_vector_type(4))) float f32x4;
typedef __attribute__((ext_vector_type(4))) unsigned int u32x4;

__device__ __forceinline__ float sigmoidf_fast(float x) {
  return 1.0f / (1.0f + __expf(-x));
}
__device__ __forceinline__ float tanhf_fast(float x) {
  return 2.0f / (1.0f + __expf(-2.0f * x)) - 1.0f;
}
__device__ __forceinline__ unsigned short f2bf_rne(float x) {
  union { float f; unsigned u; } v; v.f = x;
  unsigned r = v.u + 0x7fffu + ((v.u >> 16) & 1u);
  return (unsigned short)(r >> 16);
}
__device__ __forceinline__ float bf2f(unsigned short h) {
  union { unsigned u; float f; } v; v.u = ((unsigned)h) << 16;
  return v.f;
}

// R12 = R10 exactly (R11's three changes reverted: VGPR back to ~104,
// W_ih/bias in LDS, x-proj in act phase) EXCEPT the fast-path poll:
// R11's regression (+2.5us/step at escape 16->48) proved detection happens
// via the MALL escape probe, not the sc0/L2 probes. So each poll iteration
// now issues the L2 probe AND the MALL probe back-to-back with ONE
// vmcnt(0) drain and takes the max: poll cycle ~700 cyc (one MALL round
// trip) instead of R10's ~3900-cyc probe-train cycle. Deadlock-free by
// construction (MALL copy probed every iteration). Publish stays dual.
__global__ __launch_bounds__(256, 2) void lstm_persist(
    const float* __restrict__ strokes, const float* __restrict__ W_ih,
    const float* __restrict__ W_hh, const float* __restrict__ b_ih,
    const float* __restrict__ b_hh, const float* __restrict__ W_out,
    const float* __restrict__ b_out, float* __restrict__ out,
    unsigned short* __restrict__ hbuf,   // 2 slots * 256KB, member-major
    int* __restrict__ flagsML,           // 8*32*16 ints, MALL copy (poison<0)
    int* __restrict__ flagsL2,           // 8*32*16 ints, L2 copy   (poison<0)
    int* __restrict__ xcd_ids,           // 256 ints (poison < 0)
    int* __restrict__ vflag)             // 8*16 ints verdicts (poison < 0)
{
  const int tid  = threadIdx.x;
  const int bid  = blockIdx.x;
  const int bt   = bid & 7;      // batch tile / barrier group
  const int ht   = bid >> 3;     // hidden tile 0..31 / group member
  const int wv   = tid >> 6;     // wave id = gate type 0..3 (i,f,g,o)
  const int lane = tid & 63;
  const int n16  = lane & 15;
  const int q    = lane >> 4;

  __shared__ unsigned short h_lds[32 * LMEM];     // 48KB member-major h tile
  __shared__ float g_lds[4][MB][17];              // gate values, padded
  __shared__ float wih_lds[4][HB][INDIM];
  __shared__ float bias_lds[4][HB];
  __shared__ int fast_s;

  // ---- publish my XCC id (device scope)
  unsigned xcc;
  asm volatile("s_getreg_b32 %0, hwreg(HW_REG_XCC_ID)" : "=s"(xcc));
  xcc &= 0xfu;
  if (tid == 0) {
    __hip_atomic_store(&xcd_ids[bid], (int)xcc, __ATOMIC_RELAXED,
                       __HIP_MEMORY_SCOPE_AGENT);
  }
  // ---- leader (bid<8) computes group-uniform verdict, BOUNDED poll
  if (bid < 8 && wv == 0) {
    int other = (int)xcc;
    if (lane < 32) {
      const int* xp = &xcd_ids[bid + 8 * lane];
      other = -1;
      for (int it = 0; it < 16384 && other < 0; ++it) {
        other = __hip_atomic_load(xp, __ATOMIC_RELAXED, __HIP_MEMORY_SCOPE_AGENT);
      }
    }
    unsigned long long ok = __ballot(other == (int)xcc);
    if (lane == 0) {
      __hip_atomic_store(&vflag[bid * 16], (ok == ~0ull) ? 2 : 1,
                         __ATOMIC_RELAXED, __HIP_MEMORY_SCOPE_AGENT);
    }
  }
  if (tid == 0) {   // wait leader (co-resident, bounded work -> terminates)
    int v;
    do {
      v = __hip_atomic_load(&vflag[bt * 16], __ATOMIC_RELAXED,
                            __HIP_MEMORY_SCOPE_AGENT);
    } while (v <= 0);
    fast_s = (v == 2) ? 1 : 0;
  }

  // ---- preload W_ih slice + combined biases into LDS
  if (tid < 64) {
    int g = tid >> 4, j = tid & 15;
    int r = g * HID + ht * HB + j;
    #pragma unroll
    for (int i = 0; i < INDIM; ++i) wih_lds[g][j][i] = W_ih[r * INDIM + i];
    bias_lds[g][j] = b_ih[r] + b_hh[r];
  }

  // ---- preload W_hh as bf16 MFMA B-fragments, rotated: wfrag[i] <-> kb=(wv*4+i)&15
  short8 wfrag[16];
  {
    const float* wr = W_hh + (size_t)(wv * HID + ht * HB + n16) * HID;
    #pragma unroll
    for (int i = 0; i < 16; ++i) {
      const int kb = (wv * 4 + i) & 15;
      const float* p = wr + kb * 32 + q * 8;
      short8 f;
      #pragma unroll
      for (int j = 0; j < 8; ++j) f[j] = (short)f2bf_rne(p[j]);
      wfrag[i] = f;
    }
  }
  __syncthreads();
  const bool fast = fast_s != 0;

  // activation-phase mapping: thread -> (batch row am, hidden pair aj)
  const int am = tid >> 3;            // 0..31
  const int aj = (tid & 7) * 2;       // 0,2,..,14
  const int ab = bt * MB + am;        // global batch row
  const int j0 = wv * 8;              // this wave's first member
  float c0 = 0.f, c1 = 0.f;

  for (int t = 0; t < SEQ; ++t) {
    unsigned short* hprev = hbuf + (((t & 1) ^ 1) ? (SLOT_BYTES / 2) : 0);
    unsigned short* hcur  = hbuf + ((t & 1) ? (SLOT_BYTES / 2) : 0);

    const float* sp = strokes + ((size_t)ab * SEQ + t) * INDIM;
    float s0 = sp[0], s1 = sp[1], s2 = sp[2], s3 = sp[3], s4 = sp[4];

    f32x4 acc[2][2] = {};
    if (t > 0) {
      // ---- poll 8 members x 4 wave-flags (lanes 0..31): fused dual-probe
      if (lane < 32) {
        const int fi = (bt * 32 + (j0 + (lane >> 2))) * 16 + (lane & 3) * 4;
        const int* fpL = &flagsL2[fi];
        const int* fpM = &flagsML[fi];
        if (fast) {
          int v;
          do {
            int v1, v2;
            asm volatile("global_load_dword %0, %2, off sc0\n\t"
                         "global_load_dword %1, %3, off sc0 sc1\n\t"
                         "s_waitcnt vmcnt(0)"
                         : "=v"(v1), "=v"(v2)
                         : "v"(fpL), "v"(fpM)
                         : "memory");
            v = v1 > v2 ? v1 : v2;
          } while (v < t);
        } else {
          while (__hip_atomic_load(fpM, __ATOMIC_RELAXED,
                                   __HIP_MEMORY_SCOPE_AGENT) < t) { }
        }
      }
      // ---- stage this wave's 8 members (8 x 1KB) into LDS
      const char* base = reinterpret_cast<const char*>(hprev) + bt * 32768;
      u32x4 tmp[8];
      if (fast) {
        #pragma unroll
        for (int m = 0; m < 8; ++m)
          asm volatile("global_load_dwordx4 %0, %1, off sc0"
                       : "=v"(tmp[m])
                       : "v"(base + (j0 + m) * 1024 + lane * 16) : "memory");
      } else {
        #pragma unroll
        for (int m = 0; m < 8; ++m)
          asm volatile("global_load_dwordx4 %0, %1, off sc0 sc1"
                       : "=v"(tmp[m])
                       : "v"(base + (j0 + m) * 1024 + lane * 16) : "memory");
      }
      asm volatile("s_waitcnt vmcnt(0)" ::: "memory");
      #pragma unroll
      for (int m = 0; m < 8; ++m) {
        // bytes lane*16 of member block -> row = lane>>1, half = lane&1
        *reinterpret_cast<u32x4*>(
            &h_lds[(j0 + m) * LMEM + (lane >> 1) * LROW + (lane & 1) * 8]) = tmp[m];
      }

      // ---- early MFMA: the 4 kb this wave itself staged (i = 0..3)
      #pragma unroll
      for (int i = 0; i < 4; ++i) {
        const int kb   = wv * 4 + i;               // own range, <16
        const int jm   = kb * 2 + (q >> 1);
        const int koff = jm * LMEM + (q & 1) * 8;
        #pragma unroll
        for (int mt = 0; mt < 2; ++mt) {
          const int row = mt * 16 + n16;
          const short8 a = *reinterpret_cast<const short8*>(
              &h_lds[koff + row * LROW]);
          acc[mt][i & 1] = __builtin_amdgcn_mfma_f32_16x16x32_bf16(
              a, wfrag[i], acc[mt][i & 1], 0, 0, 0);
        }
      }
      __syncthreads();   // sync#1: all waves' staging visible
      #pragma unroll
      for (int i = 4; i < 16; ++i) {
        const int kb   = (wv * 4 + i) & 15;
        const int jm   = kb * 2 + (q >> 1);
        const int koff = jm * LMEM + (q & 1) * 8;
        #pragma unroll
        for (int mt = 0; mt < 2; ++mt) {
          const int row = mt * 16 + n16;
          const short8 a = *reinterpret_cast<const short8*>(
              &h_lds[koff + row * LROW]);
          acc[mt][i & 1] = __builtin_amdgcn_mfma_f32_16x16x32_bf16(
              a, wfrag[i], acc[mt][i & 1], 0, 0, 0);
        }
      }
    }

    // C-layout: col = lane&15, row = q*4 + reg
    #pragma unroll
    for (int mt = 0; mt < 2; ++mt) {
      #pragma unroll
      for (int r = 0; r < 4; ++r) {
        g_lds[wv][mt * 16 + q * 4 + r][n16] = acc[mt][0][r] + acc[mt][1][r];
      }
    }
    __syncthreads();   // sync#2: gates visible to all waves

    float hv[2];
    #pragma unroll
    for (int e = 0; e < 2; ++e) {
      int j = aj + e;
      float pre[4];
      #pragma unroll
      for (int g = 0; g < 4; ++g) {
        pre[g] = bias_lds[g][j] + g_lds[g][am][j]
               + s0 * wih_lds[g][j][0] + s1 * wih_lds[g][j][1]
               + s2 * wih_lds[g][j][2] + s3 * wih_lds[g][j][3]
               + s4 * wih_lds[g][j][4];
      }
      float ig = sigmoidf_fast(pre[0]);
      float fg = sigmoidf_fast(pre[1]);
      float gg = tanhf_fast(pre[2]);
      float og = sigmoidf_fast(pre[3]);
      float& c = e ? c1 : c0;
      c = fg * c + ig * gg;
      hv[e] = og * tanhf_fast(c);
    }
    // h store, member-major: member ht's 1KB at bt*32KB + ht*1KB
    unsigned pack = (unsigned)f2bf_rne(hv[0]) | ((unsigned)f2bf_rne(hv[1]) << 16);
    unsigned* hp = reinterpret_cast<unsigned*>(
        reinterpret_cast<char*>(hcur) + bt * 32768 + ht * 1024 + am * 32 + aj * 2);
    if (fast) {
      asm volatile("global_store_dword %0, %1, off sc0"
                   :: "v"(hp), "v"(pack) : "memory");
    } else {
      __hip_atomic_store(hp, pack, __ATOMIC_RELAXED, __HIP_MEMORY_SCOPE_AGENT);
    }

    // ---- per-wave publish: drain OWN wave's h stores, then flag (no sync#3)
    asm volatile("s_waitcnt vmcnt(0)" ::: "memory");
    const int gen = t + 1;
    if (lane == 0) {
      const int fi = (bt * 32 + ht) * 16 + wv * 4;
      if (fast) {
        asm volatile("global_store_dword %0, %1, off sc0"
                     :: "v"(&flagsL2[fi]), "v"(gen) : "memory");
      }
      __hip_atomic_store(&flagsML[fi], gen, __ATOMIC_RELAXED,
                         __HIP_MEMORY_SCOPE_AGENT);   // MALL copy
    }
    // next iteration's poll (or the final-proj poll) is the consumer wait
  }

  // ---- final projection: member ht==0 of each group, 32 rows.
  if (ht == 0) {
    if (lane < 32) {
      const int fi = (bt * 32 + (j0 + (lane >> 2))) * 16 + (lane & 3) * 4;
      const int* fpL = &flagsL2[fi];
      const int* fpM = &flagsML[fi];
      if (fast) {
        int v;
        do {
          int v1, v2;
          asm volatile("global_load_dword %0, %2, off sc0\n\t"
                       "global_load_dword %1, %3, off sc0 sc1\n\t"
                       "s_waitcnt vmcnt(0)"
                       : "=v"(v1), "=v"(v2)
                       : "v"(fpL), "v"(fpM)
                       : "memory");
          v = v1 > v2 ? v1 : v2;
        } while (v < SEQ);
      } else {
        while (__hip_atomic_load(fpM, __ATOMIC_RELAXED,
                                 __HIP_MEMORY_SCOPE_AGENT) < SEQ) { }
      }
    }
    const char* base = reinterpret_cast<const char*>(hbuf)
                     + ((SEQ - 1) & 1) * SLOT_BYTES + bt * 32768;
    u32x4 tmp[8];
    if (fast) {
      #pragma unroll
      for (int m = 0; m < 8; ++m)
        asm volatile("global_load_dwordx4 %0, %1, off sc0"
                     : "=v"(tmp[m])
                     : "v"(base + (j0 + m) * 1024 + lane * 16) : "memory");
    } else {
      #pragma unroll
      for (int m = 0; m < 8; ++m)
        asm volatile("global_load_dwordx4 %0, %1, off sc0 sc1"
                     : "=v"(tmp[m])
                     : "v"(base + (j0 + m) * 1024 + lane * 16) : "memory");
    }
    asm volatile("s_waitcnt vmcnt(0)" ::: "memory");
    #pragma unroll
    for (int m = 0; m < 8; ++m) {
      *reinterpret_cast<u32x4*>(
          &h_lds[(j0 + m) * LMEM + (lane >> 1) * LROW + (lane & 1) * 8]) = tmp[m];
    }
    __syncthreads();
    if (tid < 32) {
      const int b = bt * MB + tid;
      float s = 0.f;
      for (int k = 0; k < HID; ++k) {
        s += bf2f(h_lds[(k >> 4) * LMEM + tid * LROW + (k & 15)]) * W_out[k];
      }
      float raw = s + b_out[0];
      float lr = raw > 0.f ? raw : 0.1f * raw;
      out[b] = 1.0f / (1.0f + __expf(-lr));
    }
  }
}

extern "C" void kernel_launch(void* const* d_in, const int* in_sizes, int n_in,
                              void* d_out, int out_size, void* d_ws, size_t ws_size,
                              hipStream_t stream) {
  const float* strokes = (const float*)d_in[0];
  const float* W_ih    = (const float*)d_in[1];
  const float* W_hh    = (const float*)d_in[2];
  const float* b_ih    = (const float*)d_in[3];
  const float* b_hh    = (const float*)d_in[4];
  const float* W_out   = (const float*)d_in[5];
  const float* b_out   = (const float*)d_in[6];
  float* out = (float*)d_out;

  char* ws = (char*)d_ws;
  unsigned short* hbuf = (unsigned short*)ws;                 // 512 KB (2 slots)
  size_t off = (size_t)2 * SLOT_BYTES;
  int* flagsML = (int*)(ws + off);  off += 16384;             // 16 KB
  int* flagsL2 = (int*)(ws + off);  off += 16384;             // 16 KB
  int* xcd_ids = (int*)(ws + off);  off += 1024;              // 1 KB
  int* vflag   = (int*)(ws + off);                            // 512 B

  lstm_persist<<<NBLK, 256, 0, stream>>>(strokes, W_ih, W_hh, b_ih, b_hh,
                                         W_out, b_out, out, hbuf,
                                         flagsML, flagsL2, xcd_ids, vflag);
}

// Round 13
// 854.578 us; speedup vs baseline: 1.9393x; 1.2244x over previous
//
#include <hip/hip_runtime.h>
#include <hip/hip_bf16.h>

#define BATCH 256
#define SEQ   250
#define HID   512
#define INDIM 5

#define NBLK  512
#define MB    16   // batch rows per block (16 batch tiles = 16 independent chains)
#define HB    16   // hidden units per block (32 hidden tiles = 32 group members)

// member-major h buffers: slot (2) | group bt (16) | member j (32) | 512B
//   member block global: j*512 + row*32 + col*2   (16 rows x 16 cols bf16)
// LDS copy: 48B row stride (2-way max bank aliasing = free)
#define LROW 24          // ushorts per LDS row (48B)
#define LMEM 384         // ushorts per member block (16*24)
#define SLOT_BYTES (BATCH * HID * 2)   // 256KB per slot

typedef __attribute__((ext_vector_type(8))) short short8;
typedef __attribute__((ext_vector_type(4))) float f32x4;
typedef __attribute__((ext_vector_type(4))) unsigned int u32x4;

__device__ __forceinline__ float sigmoidf_fast(float x) {
  return 1.0f / (1.0f + __expf(-x));
}
__device__ __forceinline__ float tanhf_fast(float x) {
  return 2.0f / (1.0f + __expf(-2.0f * x)) - 1.0f;
}
__device__ __forceinline__ unsigned short f2bf_rne(float x) {
  union { float f; unsigned u; } v; v.f = x;
  unsigned r = v.u + 0x7fffu + ((v.u >> 16) & 1u);
  return (unsigned short)(r >> 16);
}
__device__ __forceinline__ float bf2f(unsigned short h) {
  union { unsigned u; float f; } v; v.u = ((unsigned)h) << 16;
  return v.f;
}

// R13 = R12's protocol (fused L2+MALL dual-probe poll -- R11/R12 proved
// detection rides the MALL probe; dual publish; per-(member,wave) flags;
// 2 syncs/step) on a HALVED batch tile: MB=16 -> 512 blocks, 2 blocks/CU
// from DIFFERENT independent group-chains. While one chain's waves spin on
// flags, the co-resident chain's waves compute -- the CU hides the spin
// latency that dominated R12's step. Per-chain step also shrinks (~40%:
// 16KB staged, half the MFMA/LDS, 1 act cell/thread). Group->XCD
// co-location: bid = ht*16+bt -> bid%8 = bt%8 (verdict check covers any
// other mapping).
__global__ __launch_bounds__(256, 2) void lstm_persist(
    const float* __restrict__ strokes, const float* __restrict__ W_ih,
    const float* __restrict__ W_hh, const float* __restrict__ b_ih,
    const float* __restrict__ b_hh, const float* __restrict__ W_out,
    const float* __restrict__ b_out, float* __restrict__ out,
    unsigned short* __restrict__ hbuf,   // 2 slots * 256KB, member-major
    int* __restrict__ flagsML,           // 16*32*16 ints, MALL copy (poison<0)
    int* __restrict__ flagsL2,           // 16*32*16 ints, L2 copy   (poison<0)
    int* __restrict__ xcd_ids,           // 512 ints (poison < 0)
    int* __restrict__ vflag)             // 16*16 ints verdicts (poison < 0)
{
  const int tid  = threadIdx.x;
  const int bid  = blockIdx.x;
  const int bt   = bid & 15;     // batch tile / chain id (16 chains)
  const int ht   = bid >> 4;     // hidden tile 0..31 / group member
  const int wv   = tid >> 6;     // wave id = gate type 0..3 (i,f,g,o)
  const int lane = tid & 63;
  const int n16  = lane & 15;
  const int q    = lane >> 4;

  __shared__ unsigned short h_lds[32 * LMEM];     // 24KB member-major h tile
  __shared__ float g_lds[4][MB][17];              // gate values, padded
  __shared__ float wih_lds[4][HB][INDIM];
  __shared__ float bias_lds[4][HB];
  __shared__ int fast_s;

  // ---- publish my XCC id (device scope)
  unsigned xcc;
  asm volatile("s_getreg_b32 %0, hwreg(HW_REG_XCC_ID)" : "=s"(xcc));
  xcc &= 0xfu;
  if (tid == 0) {
    __hip_atomic_store(&xcd_ids[bid], (int)xcc, __ATOMIC_RELAXED,
                       __HIP_MEMORY_SCOPE_AGENT);
  }
  // ---- leader (bid<16, i.e. ht==0) computes group verdict, BOUNDED poll
  if (bid < 16 && wv == 0) {
    int other = (int)xcc;
    if (lane < 32) {
      const int* xp = &xcd_ids[bid + 16 * lane];
      other = -1;
      for (int it = 0; it < 16384 && other < 0; ++it) {
        other = __hip_atomic_load(xp, __ATOMIC_RELAXED, __HIP_MEMORY_SCOPE_AGENT);
      }
    }
    unsigned long long ok = __ballot(other == (int)xcc);
    if (lane == 0) {
      __hip_atomic_store(&vflag[bid * 16], (ok == ~0ull) ? 2 : 1,
                         __ATOMIC_RELAXED, __HIP_MEMORY_SCOPE_AGENT);
    }
  }
  if (tid == 0) {   // wait leader (co-resident, bounded work -> terminates)
    int v;
    do {
      v = __hip_atomic_load(&vflag[bt * 16], __ATOMIC_RELAXED,
                            __HIP_MEMORY_SCOPE_AGENT);
    } while (v <= 0);
    fast_s = (v == 2) ? 1 : 0;
  }

  // ---- preload W_ih slice + combined biases into LDS
  if (tid < 64) {
    int g = tid >> 4, j = tid & 15;
    int r = g * HID + ht * HB + j;
    #pragma unroll
    for (int i = 0; i < INDIM; ++i) wih_lds[g][j][i] = W_ih[r * INDIM + i];
    bias_lds[g][j] = b_ih[r] + b_hh[r];
  }

  // ---- preload W_hh as bf16 MFMA B-fragments, rotated: wfrag[i] <-> kb=(wv*4+i)&15
  short8 wfrag[16];
  {
    const float* wr = W_hh + (size_t)(wv * HID + ht * HB + n16) * HID;
    #pragma unroll
    for (int i = 0; i < 16; ++i) {
      const int kb = (wv * 4 + i) & 15;
      const float* p = wr + kb * 32 + q * 8;
      short8 f;
      #pragma unroll
      for (int j = 0; j < 8; ++j) f[j] = (short)f2bf_rne(p[j]);
      wfrag[i] = f;
    }
  }
  __syncthreads();
  const bool fast = fast_s != 0;

  // activation-phase mapping: thread -> (batch row am, hidden col aj): 1 cell
  const int am = tid >> 4;            // 0..15
  const int aj = tid & 15;            // 0..15
  const int ab = bt * MB + am;        // global batch row
  const int j0 = wv * 8;              // this wave's first member
  float c0 = 0.f;

  for (int t = 0; t < SEQ; ++t) {
    unsigned short* hprev = hbuf + (((t & 1) ^ 1) ? (SLOT_BYTES / 2) : 0);
    unsigned short* hcur  = hbuf + ((t & 1) ? (SLOT_BYTES / 2) : 0);

    const float* sp = strokes + ((size_t)ab * SEQ + t) * INDIM;
    float s0 = sp[0], s1 = sp[1], s2 = sp[2], s3 = sp[3], s4 = sp[4];

    f32x4 acc[2] = {};
    if (t > 0) {
      // ---- poll 8 members x 4 wave-flags (lanes 0..31): fused dual-probe
      if (lane < 32) {
        const int fi = (bt * 32 + (j0 + (lane >> 2))) * 16 + (lane & 3) * 4;
        const int* fpL = &flagsL2[fi];
        const int* fpM = &flagsML[fi];
        if (fast) {
          int v;
          do {
            int v1, v2;
            asm volatile("global_load_dword %0, %2, off sc0\n\t"
                         "global_load_dword %1, %3, off sc0 sc1\n\t"
                         "s_waitcnt vmcnt(0)"
                         : "=v"(v1), "=v"(v2)
                         : "v"(fpL), "v"(fpM)
                         : "memory");
            v = v1 > v2 ? v1 : v2;
          } while (v < t);
        } else {
          while (__hip_atomic_load(fpM, __ATOMIC_RELAXED,
                                   __HIP_MEMORY_SCOPE_AGENT) < t) { }
        }
      }
      // ---- stage this wave's 8 members (8 x 512B = 4KB) into LDS
      const char* base = reinterpret_cast<const char*>(hprev) + bt * 16384;
      u32x4 tmp[4];
      if (fast) {
        #pragma unroll
        for (int i = 0; i < 4; ++i) {
          const int idx = i * 64 + lane;    // 16B chunk in wave's 4KB region
          asm volatile("global_load_dwordx4 %0, %1, off sc0"
                       : "=v"(tmp[i])
                       : "v"(base + (size_t)(j0 * 512) + idx * 16) : "memory");
        }
      } else {
        #pragma unroll
        for (int i = 0; i < 4; ++i) {
          const int idx = i * 64 + lane;
          asm volatile("global_load_dwordx4 %0, %1, off sc0 sc1"
                       : "=v"(tmp[i])
                       : "v"(base + (size_t)(j0 * 512) + idx * 16) : "memory");
        }
      }
      asm volatile("s_waitcnt vmcnt(0)" ::: "memory");
      #pragma unroll
      for (int i = 0; i < 4; ++i) {
        const int idx = i * 64 + lane;
        const int m   = j0 + (idx >> 5);   // member
        const int c   = idx & 31;          // 16B chunk in member (32/row-pair)
        *reinterpret_cast<u32x4*>(
            &h_lds[m * LMEM + (c >> 1) * LROW + (c & 1) * 8]) = tmp[i];
      }

      // ---- early MFMA: the 4 kb this wave itself staged (i = 0..3)
      #pragma unroll
      for (int i = 0; i < 4; ++i) {
        const int kb   = wv * 4 + i;               // own range, <16
        const int jm   = kb * 2 + (q >> 1);
        const short8 a = *reinterpret_cast<const short8*>(
            &h_lds[jm * LMEM + n16 * LROW + (q & 1) * 8]);
        acc[i & 1] = __builtin_amdgcn_mfma_f32_16x16x32_bf16(
            a, wfrag[i], acc[i & 1], 0, 0, 0);
      }
      __syncthreads();   // sync#1: all waves' staging visible
      #pragma unroll
      for (int i = 4; i < 16; ++i) {
        const int kb   = (wv * 4 + i) & 15;
        const int jm   = kb * 2 + (q >> 1);
        const short8 a = *reinterpret_cast<const short8*>(
            &h_lds[jm * LMEM + n16 * LROW + (q & 1) * 8]);
        acc[i & 1] = __builtin_amdgcn_mfma_f32_16x16x32_bf16(
            a, wfrag[i], acc[i & 1], 0, 0, 0);
      }
    }

    // C-layout: col = lane&15, row = q*4 + reg (rows 0..15 = batch)
    #pragma unroll
    for (int r = 0; r < 4; ++r) {
      g_lds[wv][q * 4 + r][n16] = acc[0][r] + acc[1][r];
    }
    __syncthreads();   // sync#2: gates visible to all waves

    // ---- act: ONE cell per thread (batch am, hidden aj)
    float pre[4];
    #pragma unroll
    for (int g = 0; g < 4; ++g) {
      pre[g] = bias_lds[g][aj] + g_lds[g][am][aj]
             + s0 * wih_lds[g][aj][0] + s1 * wih_lds[g][aj][1]
             + s2 * wih_lds[g][aj][2] + s3 * wih_lds[g][aj][3]
             + s4 * wih_lds[g][aj][4];
    }
    float ig = sigmoidf_fast(pre[0]);
    float fg = sigmoidf_fast(pre[1]);
    float gg = tanhf_fast(pre[2]);
    float og = sigmoidf_fast(pre[3]);
    c0 = fg * c0 + ig * gg;
    const float hv = og * tanhf_fast(c0);

    // h store: pair adjacent cols via shuffle, even lane stores one dword
    const float hv_n = __shfl_xor(hv, 1);
    if ((lane & 1) == 0) {
      unsigned pack = (unsigned)f2bf_rne(hv) | ((unsigned)f2bf_rne(hv_n) << 16);
      unsigned* hp = reinterpret_cast<unsigned*>(
          reinterpret_cast<char*>(hcur) + bt * 16384 + ht * 512 + am * 32 + aj * 2);
      if (fast) {
        asm volatile("global_store_dword %0, %1, off sc0"
                     :: "v"(hp), "v"(pack) : "memory");
      } else {
        __hip_atomic_store(hp, pack, __ATOMIC_RELAXED, __HIP_MEMORY_SCOPE_AGENT);
      }
    }

    // ---- per-wave publish: drain OWN wave's h stores, then flag (no sync#3)
    asm volatile("s_waitcnt vmcnt(0)" ::: "memory");
    const int gen = t + 1;
    if (lane == 0) {
      const int fi = (bt * 32 + ht) * 16 + wv * 4;
      if (fast) {
        asm volatile("global_store_dword %0, %1, off sc0"
                     :: "v"(&flagsL2[fi]), "v"(gen) : "memory");
      }
      __hip_atomic_store(&flagsML[fi], gen, __ATOMIC_RELAXED,
                         __HIP_MEMORY_SCOPE_AGENT);   // MALL copy
    }
    // next iteration's poll (or the final-proj poll) is the consumer wait
  }

  // ---- final projection: member ht==0 of each group, 16 rows.
  if (ht == 0) {
    if (lane < 32) {
      const int fi = (bt * 32 + (j0 + (lane >> 2))) * 16 + (lane & 3) * 4;
      const int* fpL = &flagsL2[fi];
      const int* fpM = &flagsML[fi];
      if (fast) {
        int v;
        do {
          int v1, v2;
          asm volatile("global_load_dword %0, %2, off sc0\n\t"
                       "global_load_dword %1, %3, off sc0 sc1\n\t"
                       "s_waitcnt vmcnt(0)"
                       : "=v"(v1), "=v"(v2)
                       : "v"(fpL), "v"(fpM)
                       : "memory");
          v = v1 > v2 ? v1 : v2;
        } while (v < SEQ);
      } else {
        while (__hip_atomic_load(fpM, __ATOMIC_RELAXED,
                                 __HIP_MEMORY_SCOPE_AGENT) < SEQ) { }
      }
    }
    const char* base = reinterpret_cast<const char*>(hbuf)
                     + ((SEQ - 1) & 1) * SLOT_BYTES + bt * 16384;
    u32x4 tmp[4];
    if (fast) {
      #pragma unroll
      for (int i = 0; i < 4; ++i) {
        const int idx = i * 64 + lane;
        asm volatile("global_load_dwordx4 %0, %1, off sc0"
                     : "=v"(tmp[i])
                     : "v"(base + (size_t)(j0 * 512) + idx * 16) : "memory");
      }
    } else {
      #pragma unroll
      for (int i = 0; i < 4; ++i) {
        const int idx = i * 64 + lane;
        asm volatile("global_load_dwordx4 %0, %1, off sc0 sc1"
                     : "=v"(tmp[i])
                     : "v"(base + (size_t)(j0 * 512) + idx * 16) : "memory");
      }
    }
    asm volatile("s_waitcnt vmcnt(0)" ::: "memory");
    #pragma unroll
    for (int i = 0; i < 4; ++i) {
      const int idx = i * 64 + lane;
      const int m   = j0 + (idx >> 5);
      const int c   = idx & 31;
      *reinterpret_cast<u32x4*>(
          &h_lds[m * LMEM + (c >> 1) * LROW + (c & 1) * 8]) = tmp[i];
    }
    __syncthreads();
    if (tid < MB) {
      const int b = bt * MB + tid;
      float s = 0.f;
      for (int k = 0; k < HID; ++k) {
        s += bf2f(h_lds[(k >> 4) * LMEM + tid * LROW + (k & 15)]) * W_out[k];
      }
      float raw = s + b_out[0];
      float lr = raw > 0.f ? raw : 0.1f * raw;
      out[b] = 1.0f / (1.0f + __expf(-lr));
    }
  }
}

extern "C" void kernel_launch(void* const* d_in, const int* in_sizes, int n_in,
                              void* d_out, int out_size, void* d_ws, size_t ws_size,
                              hipStream_t stream) {
  const float* strokes = (const float*)d_in[0];
  const float* W_ih    = (const float*)d_in[1];
  const float* W_hh    = (const float*)d_in[2];
  const float* b_ih    = (const float*)d_in[3];
  const float* b_hh    = (const float*)d_in[4];
  const float* W_out   = (const float*)d_in[5];
  const float* b_out   = (const float*)d_in[6];
  float* out = (float*)d_out;

  char* ws = (char*)d_ws;
  unsigned short* hbuf = (unsigned short*)ws;                 // 512 KB (2 slots)
  size_t off = (size_t)2 * SLOT_BYTES;
  int* flagsML = (int*)(ws + off);  off += 32768;             // 32 KB
  int* flagsL2 = (int*)(ws + off);  off += 32768;             // 32 KB
  int* xcd_ids = (int*)(ws + off);  off += 2048;              // 2 KB
  int* vflag   = (int*)(ws + off);                            // 1 KB

  lstm_persist<<<NBLK, 256, 0, stream>>>(strokes, W_ih, W_hh, b_ih, b_hh,
                                         W_out, b_out, out, hbuf,
                                         flagsML, flagsL2, xcd_ids, vflag);
}

// Round 14
// 849.116 us; speedup vs baseline: 1.9518x; 1.0064x over previous
//
#include <hip/hip_runtime.h>
#include <hip/hip_bf16.h>

#define BATCH 256
#define SEQ   250
#define HID   512
#define INDIM 5

#define NBLK  256
#define NCH   16   // independent batch chains
#define MB    16   // batch rows per chain/block
#define HB    32   // hidden cols per block per gate -> 16 members per chain
#define NMEM  16   // members per chain (HID/HB)

// member-major h buffers: slot (2) | chain bt (16) | member j (16) | 1KB
//   member block global: 16 rows (batch) x 32 cols (hidden) bf16 = 1KB
// LDS member block: 16 rows x 36 ushorts (72B: 64B data + 8B pad)
#define LROWU 36          // ushorts per LDS row
#define LMEMU 576         // ushorts per member block (16*36)
#define SLOT_BYTES (BATCH * HID * 2)   // 256KB per slot

typedef __attribute__((ext_vector_type(8))) short short8;
typedef __attribute__((ext_vector_type(4))) float f32x4;
typedef __attribute__((ext_vector_type(4))) unsigned int u32x4;

__device__ __forceinline__ float sigmoidf_fast(float x) {
  return 1.0f / (1.0f + __expf(-x));
}
__device__ __forceinline__ float tanhf_fast(float x) {
  return 2.0f / (1.0f + __expf(-2.0f * x)) - 1.0f;
}
__device__ __forceinline__ unsigned short f2bf_rne(float x) {
  union { float f; unsigned u; } v; v.f = x;
  unsigned r = v.u + 0x7fffu + ((v.u >> 16) & 1u);
  return (unsigned short)(r >> 16);
}
__device__ __forceinline__ float bf2f(unsigned short h) {
  union { unsigned u; float f; } v; v.u = ((unsigned)h) << 16;
  return v.f;
}

// R14 = R13's protocol (fused L2+MALL dual-probe poll, dual publish,
// per-(member,wave) flags, 2 syncs/step) with HALVED fan-in: HB=32 ->
// 16 members/chain (was 32). Detect straggler tail = max over 64 flags
// (was 128); kb == member (one K-block per member). A-fragments shared
// across the wave's two N-tiles: LDS reads stay 16 x b128 while MFMA
// issue doubles (cheap). wfrag = 128 VGPRs -> launch_bounds(256,1)
// (1 block/CU; all 256 co-resident).
__global__ __launch_bounds__(256, 1) void lstm_persist(
    const float* __restrict__ strokes, const float* __restrict__ W_ih,
    const float* __restrict__ W_hh, const float* __restrict__ b_ih,
    const float* __restrict__ b_hh, const float* __restrict__ W_out,
    const float* __restrict__ b_out, float* __restrict__ out,
    unsigned short* __restrict__ hbuf,   // 2 slots * 256KB, member-major
    int* __restrict__ flagsML,           // 16*16*16 ints, MALL copy (poison<0)
    int* __restrict__ flagsL2,           // 16*16*16 ints, L2 copy   (poison<0)
    int* __restrict__ xcd_ids,           // 256 ints (poison < 0)
    int* __restrict__ vflag)             // 16*16 ints verdicts (poison < 0)
{
  const int tid  = threadIdx.x;
  const int bid  = blockIdx.x;
  const int bt   = bid & 15;     // chain id (16 chains)
  const int ht   = bid >> 4;     // member 0..15
  const int wv   = tid >> 6;     // wave id = gate type 0..3 (i,f,g,o)
  const int lane = tid & 63;
  const int n16  = lane & 15;
  const int q    = lane >> 4;

  __shared__ unsigned short h_lds[NMEM * LMEMU];  // 18KB member-major h tile
  __shared__ float g_lds[4][MB][33];              // gates, padded
  __shared__ float wih_lds[4][HB][INDIM];
  __shared__ float bias_lds[4][HB];
  __shared__ int fast_s;

  // ---- publish my XCC id (device scope)
  unsigned xcc;
  asm volatile("s_getreg_b32 %0, hwreg(HW_REG_XCC_ID)" : "=s"(xcc));
  xcc &= 0xfu;
  if (tid == 0) {
    __hip_atomic_store(&xcd_ids[bid], (int)xcc, __ATOMIC_RELAXED,
                       __HIP_MEMORY_SCOPE_AGENT);
  }
  // ---- leader (ht==0 i.e. bid<16) computes chain verdict, BOUNDED poll
  if (bid < 16 && wv == 0) {
    int other = (int)xcc;
    if (lane < NMEM) {
      const int* xp = &xcd_ids[bid + 16 * lane];
      other = -1;
      for (int it = 0; it < 16384 && other < 0; ++it) {
        other = __hip_atomic_load(xp, __ATOMIC_RELAXED, __HIP_MEMORY_SCOPE_AGENT);
      }
    }
    unsigned long long ok = __ballot(other == (int)xcc);
    if (lane == 0) {
      __hip_atomic_store(&vflag[bid * 16], (ok == ~0ull) ? 2 : 1,
                         __ATOMIC_RELAXED, __HIP_MEMORY_SCOPE_AGENT);
    }
  }
  if (tid == 0) {   // wait leader (co-resident, bounded work -> terminates)
    int v;
    do {
      v = __hip_atomic_load(&vflag[bt * 16], __ATOMIC_RELAXED,
                            __HIP_MEMORY_SCOPE_AGENT);
    } while (v <= 0);
    fast_s = (v == 2) ? 1 : 0;
  }

  // ---- preload W_ih slice + combined biases into LDS (HB=32 per gate)
  if (tid < 128) {
    int g = tid >> 5, j = tid & 31;
    int r = g * HID + ht * HB + j;
    #pragma unroll
    for (int i = 0; i < INDIM; ++i) wih_lds[g][j][i] = W_ih[r * INDIM + i];
    bias_lds[g][j] = b_ih[r] + b_hh[r];
  }

  // ---- preload W_hh as bf16 MFMA B-fragments, 2 N-tiles per wave,
  // rotated: wfrag[i][nt] <-> kb=(wv*4+i)&15
  short8 wfrag[16][2];
  {
    #pragma unroll
    for (int i = 0; i < 16; ++i) {
      const int kb = (wv * 4 + i) & 15;
      #pragma unroll
      for (int nt = 0; nt < 2; ++nt) {
        const float* p = W_hh
            + (size_t)(wv * HID + ht * HB + nt * 16 + n16) * HID
            + kb * 32 + q * 8;
        short8 f;
        #pragma unroll
        for (int j = 0; j < 8; ++j) f[j] = (short)f2bf_rne(p[j]);
        wfrag[i][nt] = f;
      }
    }
  }
  __syncthreads();
  const bool fast = fast_s != 0;

  // activation-phase mapping: thread -> (batch row am, hidden pair ajp)
  const int am  = tid >> 4;           // 0..15
  const int ajp = (tid & 15) * 2;     // 0,2,..,30
  const int ab  = bt * MB + am;       // global batch row
  const int j0m = wv * 4;             // this wave's first member
  float c0 = 0.f, c1 = 0.f;

  for (int t = 0; t < SEQ; ++t) {
    unsigned short* hprev = hbuf + (((t & 1) ^ 1) ? (SLOT_BYTES / 2) : 0);
    unsigned short* hcur  = hbuf + ((t & 1) ? (SLOT_BYTES / 2) : 0);

    const float* sp = strokes + ((size_t)ab * SEQ + t) * INDIM;
    float s0 = sp[0], s1 = sp[1], s2 = sp[2], s3 = sp[3], s4 = sp[4];

    f32x4 acc[2][2] = {};   // [ntile][parity]
    if (t > 0) {
      // ---- poll 4 members x 4 wave-flags (lanes 0..15): fused dual-probe
      if (lane < 16) {
        const int fi = (bt * 16 + (j0m + (lane >> 2))) * 16 + (lane & 3) * 4;
        const int* fpL = &flagsL2[fi];
        const int* fpM = &flagsML[fi];
        if (fast) {
          int v;
          do {
            int v1, v2;
            asm volatile("global_load_dword %0, %2, off sc0\n\t"
                         "global_load_dword %1, %3, off sc0 sc1\n\t"
                         "s_waitcnt vmcnt(0)"
                         : "=v"(v1), "=v"(v2)
                         : "v"(fpL), "v"(fpM)
                         : "memory");
            v = v1 > v2 ? v1 : v2;
          } while (v < t);
        } else {
          while (__hip_atomic_load(fpM, __ATOMIC_RELAXED,
                                   __HIP_MEMORY_SCOPE_AGENT) < t) { }
        }
      }
      // ---- stage this wave's 4 members (4 x 1KB) into LDS
      const char* base = reinterpret_cast<const char*>(hprev) + bt * 16384
                       + j0m * 1024;
      u32x4 tmp[4];
      if (fast) {
        #pragma unroll
        for (int i = 0; i < 4; ++i)
          asm volatile("global_load_dwordx4 %0, %1, off sc0"
                       : "=v"(tmp[i])
                       : "v"(base + (size_t)(i * 64 + lane) * 16) : "memory");
      } else {
        #pragma unroll
        for (int i = 0; i < 4; ++i)
          asm volatile("global_load_dwordx4 %0, %1, off sc0 sc1"
                       : "=v"(tmp[i])
                       : "v"(base + (size_t)(i * 64 + lane) * 16) : "memory");
      }
      asm volatile("s_waitcnt vmcnt(0)" ::: "memory");
      #pragma unroll
      for (int i = 0; i < 4; ++i) {
        const int idx = i * 64 + lane;     // 16B chunk index in wave's 4KB
        const int m   = j0m + (idx >> 6);  // member (64 chunks each)
        const int c   = idx & 63;          // chunk in member
        // member block: row = c>>2 (4 chunks/64B row), cpos = c&3
        *reinterpret_cast<u32x4*>(
            &h_lds[m * LMEMU + (c >> 2) * LROWU + (c & 3) * 8]) = tmp[i];
      }

      // ---- early MFMA: the 4 kb (== members) this wave itself staged
      #pragma unroll
      for (int i = 0; i < 4; ++i) {
        const int kb = wv * 4 + i;         // own member, <16
        const short8 a = *reinterpret_cast<const short8*>(
            &h_lds[kb * LMEMU + n16 * LROWU + q * 8]);
        #pragma unroll
        for (int nt = 0; nt < 2; ++nt)
          acc[nt][i & 1] = __builtin_amdgcn_mfma_f32_16x16x32_bf16(
              a, wfrag[i][nt], acc[nt][i & 1], 0, 0, 0);
      }
      __syncthreads();   // sync#1: all waves' staging visible
      #pragma unroll
      for (int i = 4; i < 16; ++i) {
        const int kb = (wv * 4 + i) & 15;
        const short8 a = *reinterpret_cast<const short8*>(
            &h_lds[kb * LMEMU + n16 * LROWU + q * 8]);
        #pragma unroll
        for (int nt = 0; nt < 2; ++nt)
          acc[nt][i & 1] = __builtin_amdgcn_mfma_f32_16x16x32_bf16(
              a, wfrag[i][nt], acc[nt][i & 1], 0, 0, 0);
      }
    }

    // C-layout per N-tile: col = nt*16 + (lane&15), row = q*4 + reg
    #pragma unroll
    for (int nt = 0; nt < 2; ++nt) {
      #pragma unroll
      for (int r = 0; r < 4; ++r) {
        g_lds[wv][q * 4 + r][nt * 16 + n16] = acc[nt][0][r] + acc[nt][1][r];
      }
    }
    __syncthreads();   // sync#2: gates visible to all waves

    // ---- act: 2 cells per thread (batch am, hidden ajp, ajp+1)
    float hv[2];
    #pragma unroll
    for (int e = 0; e < 2; ++e) {
      const int j = ajp + e;
      float pre[4];
      #pragma unroll
      for (int g = 0; g < 4; ++g) {
        pre[g] = bias_lds[g][j] + g_lds[g][am][j]
               + s0 * wih_lds[g][j][0] + s1 * wih_lds[g][j][1]
               + s2 * wih_lds[g][j][2] + s3 * wih_lds[g][j][3]
               + s4 * wih_lds[g][j][4];
      }
      float ig = sigmoidf_fast(pre[0]);
      float fg = sigmoidf_fast(pre[1]);
      float gg = tanhf_fast(pre[2]);
      float og = sigmoidf_fast(pre[3]);
      float& c = e ? c1 : c0;
      c = fg * c + ig * gg;
      hv[e] = og * tanhf_fast(c);
    }
    // h store: one dword (2 bf16) into member ht's 1KB block
    unsigned pack = (unsigned)f2bf_rne(hv[0]) | ((unsigned)f2bf_rne(hv[1]) << 16);
    unsigned* hp = reinterpret_cast<unsigned*>(
        reinterpret_cast<char*>(hcur) + bt * 16384 + ht * 1024 + am * 64 + ajp * 2);
    if (fast) {
      asm volatile("global_store_dword %0, %1, off sc0"
                   :: "v"(hp), "v"(pack) : "memory");
    } else {
      __hip_atomic_store(hp, pack, __ATOMIC_RELAXED, __HIP_MEMORY_SCOPE_AGENT);
    }

    // ---- per-wave publish: drain OWN wave's h stores, then flag (no sync#3)
    asm volatile("s_waitcnt vmcnt(0)" ::: "memory");
    const int gen = t + 1;
    if (lane == 0) {
      const int fi = (bt * 16 + ht) * 16 + wv * 4;
      if (fast) {
        asm volatile("global_store_dword %0, %1, off sc0"
                     :: "v"(&flagsL2[fi]), "v"(gen) : "memory");
      }
      __hip_atomic_store(&flagsML[fi], gen, __ATOMIC_RELAXED,
                         __HIP_MEMORY_SCOPE_AGENT);   // MALL copy
    }
    // next iteration's poll (or the final-proj poll) is the consumer wait
  }

  // ---- final projection: member ht==0 of each chain, 16 rows.
  if (ht == 0) {
    if (lane < 16) {
      const int fi = (bt * 16 + (j0m + (lane >> 2))) * 16 + (lane & 3) * 4;
      const int* fpL = &flagsL2[fi];
      const int* fpM = &flagsML[fi];
      if (fast) {
        int v;
        do {
          int v1, v2;
          asm volatile("global_load_dword %0, %2, off sc0\n\t"
                       "global_load_dword %1, %3, off sc0 sc1\n\t"
                       "s_waitcnt vmcnt(0)"
                       : "=v"(v1), "=v"(v2)
                       : "v"(fpL), "v"(fpM)
                       : "memory");
          v = v1 > v2 ? v1 : v2;
        } while (v < SEQ);
      } else {
        while (__hip_atomic_load(fpM, __ATOMIC_RELAXED,
                                 __HIP_MEMORY_SCOPE_AGENT) < SEQ) { }
      }
    }
    const char* base = reinterpret_cast<const char*>(hbuf)
                     + ((SEQ - 1) & 1) * SLOT_BYTES + bt * 16384 + j0m * 1024;
    u32x4 tmp[4];
    if (fast) {
      #pragma unroll
      for (int i = 0; i < 4; ++i)
        asm volatile("global_load_dwordx4 %0, %1, off sc0"
                     : "=v"(tmp[i])
                     : "v"(base + (size_t)(i * 64 + lane) * 16) : "memory");
    } else {
      #pragma unroll
      for (int i = 0; i < 4; ++i)
        asm volatile("global_load_dwordx4 %0, %1, off sc0 sc1"
                     : "=v"(tmp[i])
                     : "v"(base + (size_t)(i * 64 + lane) * 16) : "memory");
    }
    asm volatile("s_waitcnt vmcnt(0)" ::: "memory");
    #pragma unroll
    for (int i = 0; i < 4; ++i) {
      const int idx = i * 64 + lane;
      const int m   = j0m + (idx >> 6);
      const int c   = idx & 63;
      *reinterpret_cast<u32x4*>(
          &h_lds[m * LMEMU + (c >> 2) * LROWU + (c & 3) * 8]) = tmp[i];
    }
    __syncthreads();
    if (tid < MB) {
      const int b = bt * MB + tid;
      float s = 0.f;
      for (int k = 0; k < HID; ++k) {
        s += bf2f(h_lds[(k >> 5) * LMEMU + tid * LROWU + (k & 31)]) * W_out[k];
      }
      float raw = s + b_out[0];
      float lr = raw > 0.f ? raw : 0.1f * raw;
      out[b] = 1.0f / (1.0f + __expf(-lr));
    }
  }
}

extern "C" void kernel_launch(void* const* d_in, const int* in_sizes, int n_in,
                              void* d_out, int out_size, void* d_ws, size_t ws_size,
                              hipStream_t stream) {
  const float* strokes = (const float*)d_in[0];
  const float* W_ih    = (const float*)d_in[1];
  const float* W_hh    = (const float*)d_in[2];
  const float* b_ih    = (const float*)d_in[3];
  const float* b_hh    = (const float*)d_in[4];
  const float* W_out   = (const float*)d_in[5];
  const float* b_out   = (const float*)d_in[6];
  float* out = (float*)d_out;

  char* ws = (char*)d_ws;
  unsigned short* hbuf = (unsigned short*)ws;                 // 512 KB (2 slots)
  size_t off = (size_t)2 * SLOT_BYTES;
  int* flagsML = (int*)(ws + off);  off += 16384;             // 16 KB
  int* flagsL2 = (int*)(ws + off);  off += 16384;             // 16 KB
  int* xcd_ids = (int*)(ws + off);  off += 2048;              // 2 KB
  int* vflag   = (int*)(ws + off);                            // 1 KB

  lstm_persist<<<NBLK, 256, 0, stream>>>(strokes, W_ih, W_hh, b_ih, b_hh,
                                         W_out, b_out, out, hbuf,
                                         flagsML, flagsL2, xcd_ids, vflag);
}